// Round 1
// baseline (1035.610 us; speedup 1.0000x reference)
//
#include <hip/hip_runtime.h>

#define DIM 2048
#define NH 16
#define HD 128
#define HIDDEN 5504
#define BB 2
#define TT 2048
#define M_ROWS (BB*TT)
#define QKV_N (3*DIM)
#define ATT_SCALE 0.08838834764831845f

typedef float f32x4 __attribute__((ext_vector_type(4)));
typedef __bf16 bf16x8 __attribute__((ext_vector_type(8)));

__device__ __forceinline__ float bf2f(unsigned short u){
  unsigned x = ((unsigned)u) << 16; float f; __builtin_memcpy(&f, &x, 4); return f;
}
__device__ __forceinline__ unsigned short f2bf(float f){
  unsigned x; __builtin_memcpy(&x, &f, 4);
  x = (x + 0x7fffu + ((x >> 16) & 1u)) >> 16;
  return (unsigned short)x;
}

// ---------- transpose: src f32 (K x N) -> dst bf16 (N x K) ----------
__global__ __launch_bounds__(256) void k_transpose(const float* __restrict__ src,
                                                   unsigned short* __restrict__ dst,
                                                   int K, int N){
  __shared__ float tile[64][65];
  int nb = blockIdx.x * 64, kb = blockIdx.y * 64;
  int tid = threadIdx.x, c = tid & 63, r0 = tid >> 6;
  #pragma unroll
  for (int i = 0; i < 16; i++){
    int r = i * 4 + r0;
    tile[r][c] = src[(size_t)(kb + r) * N + nb + c];
  }
  __syncthreads();
  #pragma unroll
  for (int i = 0; i < 16; i++){
    int r = i * 4 + r0;
    dst[(size_t)(nb + r) * K + kb + c] = f2bf(tile[c][r]);
  }
}

// ---------- per-(b,h) V transpose: qkv v-section (T x 128) -> Vt_g (128 x T) ----------
__global__ __launch_bounds__(256) void k_vtrans(const unsigned short* __restrict__ qkv,
                                                unsigned short* __restrict__ Vt_g){
  int bh = blockIdx.z; int b = bh >> 4, h = bh & 15;
  int tb = blockIdx.x * 64, db = blockIdx.y * 64;
  const unsigned short* Vp = qkv + (size_t)b * TT * QKV_N + 2 * DIM + h * HD;
  __shared__ unsigned short tile[64][66];
  int tid = threadIdx.x, c = tid & 63, r0 = tid >> 6;
  #pragma unroll
  for (int i = 0; i < 16; i++){
    int r = i * 4 + r0;
    tile[r][c] = Vp[(size_t)(tb + r) * QKV_N + db + c];
  }
  __syncthreads();
  #pragma unroll
  for (int i = 0; i < 16; i++){
    int r = i * 4 + r0;
    Vt_g[((size_t)bh * HD + db + r) * TT + tb + c] = tile[c][r];
  }
}

// ---------- LayerNorm: f32 row (2048) -> bf16 ----------
__global__ __launch_bounds__(256) void k_ln(const float* __restrict__ x,
                                            const float* __restrict__ g,
                                            const float* __restrict__ b,
                                            unsigned short* __restrict__ out){
  int row = blockIdx.x, tid = threadIdx.x;
  const float* xr = x + (size_t)row * DIM;
  int c0 = tid * 4, c1 = 1024 + tid * 4;
  float4 a = *(const float4*)(xr + c0);
  float4 c = *(const float4*)(xr + c1);
  float s  = a.x + a.y + a.z + a.w + c.x + c.y + c.z + c.w;
  float sq = a.x*a.x + a.y*a.y + a.z*a.z + a.w*a.w + c.x*c.x + c.y*c.y + c.z*c.z + c.w*c.w;
  #pragma unroll
  for (int off = 1; off < 64; off <<= 1){
    s  += __shfl_xor(s,  off);
    sq += __shfl_xor(sq, off);
  }
  __shared__ float red[8];
  int wave = tid >> 6;
  if ((tid & 63) == 0){ red[wave] = s; red[4 + wave] = sq; }
  __syncthreads();
  s  = red[0] + red[1] + red[2] + red[3];
  sq = red[4] + red[5] + red[6] + red[7];
  float mean = s * (1.f / DIM);
  float var  = sq * (1.f / DIM) - mean * mean;
  float rs   = rsqrtf(var + 1e-5f);
  float4 g0 = *(const float4*)(g + c0), g1 = *(const float4*)(g + c1);
  float4 b0 = *(const float4*)(b + c0), b1 = *(const float4*)(b + c1);
  ushort4 o0, o1;
  o0.x = f2bf((a.x - mean) * rs * g0.x + b0.x);
  o0.y = f2bf((a.y - mean) * rs * g0.y + b0.y);
  o0.z = f2bf((a.z - mean) * rs * g0.z + b0.z);
  o0.w = f2bf((a.w - mean) * rs * g0.w + b0.w);
  o1.x = f2bf((c.x - mean) * rs * g1.x + b1.x);
  o1.y = f2bf((c.y - mean) * rs * g1.y + b1.y);
  o1.z = f2bf((c.z - mean) * rs * g1.z + b1.z);
  o1.w = f2bf((c.w - mean) * rs * g1.w + b1.w);
  *(ushort4*)(out + (size_t)row * DIM + c0) = o0;
  *(ushort4*)(out + (size_t)row * DIM + c1) = o1;
}

// ---------- GEMM: C[M,N] = A[M,K](bf16) * Bt[N,K](bf16)^T ----------
// EPI 0: store bf16 to Cb.  EPI 1: Cf = res + acc (f32).
template<int EPI>
__global__ __launch_bounds__(256) void k_gemm(const unsigned short* __restrict__ A,
                                              const unsigned short* __restrict__ Bt,
                                              unsigned short* __restrict__ Cb,
                                              const float* __restrict__ res,
                                              float* __restrict__ Cf,
                                              int M, int N, int K){
  __shared__ __align__(16) unsigned short As[128][72];
  __shared__ __align__(16) unsigned short Bs[128][72];
  int tid = threadIdx.x;
  int wave = tid >> 6, lane = tid & 63, lg = lane >> 4, lr = lane & 15;
  int wm = wave >> 1, wn = wave & 1;
  int m0 = blockIdx.y * 128, n0 = blockIdx.x * 128;
  f32x4 acc[4][4];
  #pragma unroll
  for (int mi = 0; mi < 4; mi++)
    #pragma unroll
    for (int nj = 0; nj < 4; nj++)
      acc[mi][nj] = (f32x4)0.f;
  int srow = tid >> 3, scol = (tid & 7) * 8;
  for (int k0 = 0; k0 < K; k0 += 64){
    __syncthreads();
    #pragma unroll
    for (int i = 0; i < 4; i++){
      int r = srow + i * 32;
      *(int4*)(&As[r][scol]) = *(const int4*)(A  + (size_t)(m0 + r) * K + k0 + scol);
      *(int4*)(&Bs[r][scol]) = *(const int4*)(Bt + (size_t)(n0 + r) * K + k0 + scol);
    }
    __syncthreads();
    #pragma unroll
    for (int kk = 0; kk < 2; kk++){
      bf16x8 af[4], bfr[4];
      #pragma unroll
      for (int mi = 0; mi < 4; mi++)
        af[mi] = *(const bf16x8*)(&As[wm * 64 + mi * 16 + lr][kk * 32 + lg * 8]);
      #pragma unroll
      for (int nj = 0; nj < 4; nj++)
        bfr[nj] = *(const bf16x8*)(&Bs[wn * 64 + nj * 16 + lr][kk * 32 + lg * 8]);
      #pragma unroll
      for (int mi = 0; mi < 4; mi++)
        #pragma unroll
        for (int nj = 0; nj < 4; nj++)
          acc[mi][nj] = __builtin_amdgcn_mfma_f32_16x16x32_bf16(af[mi], bfr[nj], acc[mi][nj], 0, 0, 0);
    }
  }
  #pragma unroll
  for (int mi = 0; mi < 4; mi++){
    #pragma unroll
    for (int r = 0; r < 4; r++){
      int m = m0 + wm * 64 + mi * 16 + lg * 4 + r;
      #pragma unroll
      for (int nj = 0; nj < 4; nj++){
        int n = n0 + wn * 64 + nj * 16 + lr;
        if (EPI == 0)
          Cb[(size_t)m * N + n] = f2bf(acc[mi][nj][r]);
        else
          Cf[(size_t)m * N + n] = res[(size_t)m * N + n] + acc[mi][nj][r];
      }
    }
  }
}

// ---------- RoPE in-place on q,k sections of qkv (scale folded into q) ----------
__global__ __launch_bounds__(256) void k_rope(unsigned short* __restrict__ qkv,
                                              const float* __restrict__ cosp,
                                              const float* __restrict__ sinp){
  int gid = blockIdx.x * 256 + threadIdx.x;   // < 4096*16*64
  int m = gid >> 10;
  int rem = gid & 1023;
  int h = rem >> 6, d = rem & 63;
  int t = m & (TT - 1);
  size_t base = (size_t)m * QKV_N + h * HD;
  float c = cosp[t * 64 + d], s = sinp[t * 64 + d];
  float q1 = bf2f(qkv[base + d]), q2 = bf2f(qkv[base + 64 + d]);
  qkv[base + d]      = f2bf((q1 * c - q2 * s) * ATT_SCALE);
  qkv[base + 64 + d] = f2bf((q1 * s + q2 * c) * ATT_SCALE);
  size_t kb = base + DIM;
  float k1 = bf2f(qkv[kb + d]), k2 = bf2f(qkv[kb + 64 + d]);
  qkv[kb + d]      = f2bf(k1 * c - k2 * s);
  qkv[kb + 64 + d] = f2bf(k1 * s + k2 * c);
}

// ---------- flash attention: qkv (bf16, scaled/roped) -> O (bf16, [B*T, DIM]) ----------
__global__ __launch_bounds__(256) void k_attn(const unsigned short* __restrict__ qkv,
                                              const unsigned short* __restrict__ Vt_g,
                                              unsigned short* __restrict__ O){
  int qb = blockIdx.x;           // 0..15 (128-row q blocks)
  int bh = blockIdx.y;           // 0..31
  int b = bh >> 4, h = bh & 15;
  const unsigned short* Qp = qkv + (size_t)b * TT * QKV_N + h * HD;
  const unsigned short* Kp = Qp + DIM;
  __shared__ __align__(16) unsigned short Kt[64][136];
  __shared__ __align__(16) unsigned short Vt[128][72];
  __shared__ __align__(16) unsigned short Ps[4][32][72];
  int tid = threadIdx.x, wave = tid >> 6, lane = tid & 63, lg = lane >> 4, lr = lane & 15;
  int q0 = qb * 128 + wave * 32;
  bf16x8 qf[2][4];
  #pragma unroll
  for (int mi = 0; mi < 2; mi++)
    #pragma unroll
    for (int dc = 0; dc < 4; dc++)
      qf[mi][dc] = *(const bf16x8*)(Qp + (size_t)(q0 + mi * 16 + lr) * QKV_N + dc * 32 + lg * 8);
  f32x4 of[2][8];
  #pragma unroll
  for (int mi = 0; mi < 2; mi++)
    #pragma unroll
    for (int dj = 0; dj < 8; dj++)
      of[mi][dj] = (f32x4)0.f;
  float mrun[2] = {-1e30f, -1e30f}, lrun[2] = {0.f, 0.f};
  int ktmax = 2 * qb + 1;
  int sr = tid >> 4, sc8 = (tid & 15) * 8;   // K staging
  int vr = tid >> 3, vc8 = (tid & 7) * 8;    // V staging
  for (int kt = 0; kt <= ktmax; kt++){
    int kbase = kt * 64;
    __syncthreads();
    #pragma unroll
    for (int i = 0; i < 4; i++){
      int rr = sr + i * 16;
      *(int4*)(&Kt[rr][sc8]) = *(const int4*)(Kp + (size_t)(kbase + rr) * QKV_N + sc8);
      int dd = vr + i * 32;
      *(int4*)(&Vt[dd][vc8]) = *(const int4*)(Vt_g + ((size_t)bh * HD + dd) * TT + kbase + vc8);
    }
    __syncthreads();
    // S^T = K * Q^T  (rows=k, cols=q)
    f32x4 st[4][2];
    #pragma unroll
    for (int kj = 0; kj < 4; kj++)
      #pragma unroll
      for (int mi = 0; mi < 2; mi++)
        st[kj][mi] = (f32x4)0.f;
    #pragma unroll
    for (int kj = 0; kj < 4; kj++){
      #pragma unroll
      for (int dc = 0; dc < 4; dc++){
        bf16x8 kf = *(const bf16x8*)(&Kt[kj * 16 + lr][dc * 32 + lg * 8]);
        st[kj][0] = __builtin_amdgcn_mfma_f32_16x16x32_bf16(kf, qf[0][dc], st[kj][0], 0, 0, 0);
        st[kj][1] = __builtin_amdgcn_mfma_f32_16x16x32_bf16(kf, qf[1][dc], st[kj][1], 0, 0, 0);
      }
    }
    // causal mask (st row = k local = kj*16 + lg*4 + r ; col = q = lr)
    #pragma unroll
    for (int kj = 0; kj < 4; kj++){
      int kg = kbase + kj * 16 + lg * 4;
      #pragma unroll
      for (int mi = 0; mi < 2; mi++){
        int qg = q0 + mi * 16 + lr;
        #pragma unroll
        for (int r = 0; r < 4; r++)
          if (kg + r > qg) st[kj][mi][r] = -1e30f;
      }
    }
    // online softmax per q-column
    #pragma unroll
    for (int mi = 0; mi < 2; mi++){
      float mx = -1e30f;
      #pragma unroll
      for (int kj = 0; kj < 4; kj++)
        #pragma unroll
        for (int r = 0; r < 4; r++)
          mx = fmaxf(mx, st[kj][mi][r]);
      mx = fmaxf(mx, __shfl_xor(mx, 16));
      mx = fmaxf(mx, __shfl_xor(mx, 32));
      float mnew = fmaxf(mrun[mi], mx);
      float fsc = __expf(mrun[mi] - mnew);
      float rs = 0.f;
      #pragma unroll
      for (int kj = 0; kj < 4; kj++)
        #pragma unroll
        for (int r = 0; r < 4; r++){
          float p = __expf(st[kj][mi][r] - mnew);
          st[kj][mi][r] = p;
          rs += p;
        }
      rs += __shfl_xor(rs, 16);
      rs += __shfl_xor(rs, 32);
      lrun[mi] = lrun[mi] * fsc + rs;
      mrun[mi] = mnew;
      float fr[4];
      #pragma unroll
      for (int r = 0; r < 4; r++) fr[r] = __shfl(fsc, lg * 4 + r);
      #pragma unroll
      for (int dj = 0; dj < 8; dj++)
        #pragma unroll
        for (int r = 0; r < 4; r++)
          of[mi][dj][r] *= fr[r];
      #pragma unroll
      for (int kj = 0; kj < 4; kj++){
        ushort4 pk;
        pk.x = f2bf(st[kj][mi][0]);
        pk.y = f2bf(st[kj][mi][1]);
        pk.z = f2bf(st[kj][mi][2]);
        pk.w = f2bf(st[kj][mi][3]);
        *(ushort4*)(&Ps[wave][mi * 16 + lr][kj * 16 + lg * 4]) = pk;
      }
    }
    // PV: O += P * V
    #pragma unroll
    for (int kc = 0; kc < 2; kc++){
      bf16x8 pf0 = *(const bf16x8*)(&Ps[wave][lr][kc * 32 + lg * 8]);
      bf16x8 pf1 = *(const bf16x8*)(&Ps[wave][16 + lr][kc * 32 + lg * 8]);
      #pragma unroll
      for (int dj = 0; dj < 8; dj++){
        bf16x8 vf = *(const bf16x8*)(&Vt[dj * 16 + lr][kc * 32 + lg * 8]);
        of[0][dj] = __builtin_amdgcn_mfma_f32_16x16x32_bf16(pf0, vf, of[0][dj], 0, 0, 0);
        of[1][dj] = __builtin_amdgcn_mfma_f32_16x16x32_bf16(pf1, vf, of[1][dj], 0, 0, 0);
      }
    }
  }
  // finalize: O /= l, write bf16 (row m = b*T + t, col = h*128 + d)
  #pragma unroll
  for (int mi = 0; mi < 2; mi++){
    float inv[4];
    #pragma unroll
    for (int r = 0; r < 4; r++) inv[r] = 1.f / __shfl(lrun[mi], lg * 4 + r);
    #pragma unroll
    for (int r = 0; r < 4; r++){
      int t = q0 + mi * 16 + lg * 4 + r;
      size_t rowb = ((size_t)b * TT + t) * DIM + h * HD;
      #pragma unroll
      for (int dj = 0; dj < 8; dj++)
        O[rowb + dj * 16 + lr] = f2bf(of[mi][dj][r] * inv[r]);
    }
  }
}

// ---------- SiLU(g)*v : gv bf16 [M, 2*HIDDEN] -> act bf16 [M, HIDDEN] ----------
__global__ __launch_bounds__(256) void k_silu(const unsigned short* __restrict__ gv,
                                              unsigned short* __restrict__ act){
  int gid = blockIdx.x * 256 + threadIdx.x;  // < 4096 * 688
  unsigned m = (unsigned)gid / 688u;
  int j8 = (gid - (int)m * 688) * 8;
  const unsigned short* gp = gv + (size_t)m * (2 * HIDDEN) + j8;
  union { int4 v; unsigned short s[8]; } G, V, Ov;
  G.v = *(const int4*)(gp);
  V.v = *(const int4*)(gp + HIDDEN);
  #pragma unroll
  for (int j = 0; j < 8; j++){
    float g = bf2f(G.s[j]);
    float v = bf2f(V.s[j]);
    float sg = g / (1.f + __expf(-g));
    Ov.s[j] = f2bf(sg * v);
  }
  *(int4*)(act + (size_t)m * HIDDEN + j8) = Ov.v;
}

extern "C" void kernel_launch(void* const* d_in, const int* in_sizes, int n_in,
                              void* d_out, int out_size, void* d_ws, size_t ws_size,
                              hipStream_t stream){
  const float* x     = (const float*)d_in[0];
  const float* cosp  = (const float*)d_in[1];
  const float* sinp  = (const float*)d_in[2];
  // d_in[3] mask: implemented as hard causal
  const float* ln1g  = (const float*)d_in[4];
  const float* ln1b  = (const float*)d_in[5];
  const float* ln2g  = (const float*)d_in[6];
  const float* ln2b  = (const float*)d_in[7];
  const float* wqkv  = (const float*)d_in[8];
  const float* wout  = (const float*)d_in[9];
  const float* wgate = (const float*)d_in[10];
  const float* wdown = (const float*)d_in[11];
  float* outp = (float*)d_out;

  char* ws = (char*)d_ws;
  size_t off = 0;
  auto alloc = [&](size_t bytes) -> void* {
    void* p = ws + off;
    off += (bytes + 255) & ~(size_t)255;
    return p;
  };
  unsigned short* wqkvT  = (unsigned short*)alloc((size_t)QKV_N * DIM * 2);
  unsigned short* woutT  = (unsigned short*)alloc((size_t)DIM * DIM * 2);
  unsigned short* wgateT = (unsigned short*)alloc((size_t)2 * HIDDEN * DIM * 2);
  unsigned short* wdownT = (unsigned short*)alloc((size_t)DIM * HIDDEN * 2);
  float*          x1     = (float*)alloc((size_t)M_ROWS * DIM * 4);
  unsigned short* h1     = (unsigned short*)alloc((size_t)M_ROWS * DIM * 2); // reused as Obuf
  unsigned short* h2     = (unsigned short*)alloc((size_t)M_ROWS * DIM * 2);
  unsigned short* act    = (unsigned short*)alloc((size_t)M_ROWS * HIDDEN * 2);
  unsigned short* Vt_g   = (unsigned short*)alloc((size_t)BB * NH * HD * TT * 2);
  unsigned short* big    = (unsigned short*)alloc((size_t)M_ROWS * 2 * HIDDEN * 2); // qkv then gv
  unsigned short* qkvb = big;
  unsigned short* gvb  = big;
  unsigned short* Obuf = h1;
  (void)ws_size; (void)in_sizes; (void)n_in; (void)out_size;

  // weight transposes (f32 -> bf16, [N][K])
  k_transpose<<<dim3(QKV_N / 64, DIM / 64), 256, 0, stream>>>(wqkv, wqkvT, DIM, QKV_N);
  k_transpose<<<dim3(DIM / 64, DIM / 64), 256, 0, stream>>>(wout, woutT, DIM, DIM);
  k_transpose<<<dim3(2 * HIDDEN / 64, DIM / 64), 256, 0, stream>>>(wgate, wgateT, DIM, 2 * HIDDEN);
  k_transpose<<<dim3(DIM / 64, HIDDEN / 64), 256, 0, stream>>>(wdown, wdownT, HIDDEN, DIM);
  // LN1
  k_ln<<<M_ROWS, 256, 0, stream>>>(x, ln1g, ln1b, h1);
  // qkv = h1 @ w_qkv
  k_gemm<0><<<dim3(QKV_N / 128, M_ROWS / 128), 256, 0, stream>>>(h1, wqkvT, qkvb, nullptr, nullptr, M_ROWS, QKV_N, DIM);
  // RoPE in-place (q scaled)
  k_rope<<<(M_ROWS * NH * 64) / 256, 256, 0, stream>>>(qkvb, cosp, sinp);
  // V transpose per (b,h)
  k_vtrans<<<dim3(TT / 64, HD / 64, BB * NH), 256, 0, stream>>>(qkvb, Vt_g);
  // attention
  k_attn<<<dim3(TT / 128, BB * NH), 256, 0, stream>>>(qkvb, Vt_g, Obuf);
  // x1 = x + O @ w_out
  k_gemm<1><<<dim3(DIM / 128, M_ROWS / 128), 256, 0, stream>>>(Obuf, woutT, nullptr, x, x1, M_ROWS, DIM, DIM);
  // LN2
  k_ln<<<M_ROWS, 256, 0, stream>>>(x1, ln2g, ln2b, h2);
  // gv = h2 @ w_gate
  k_gemm<0><<<dim3(2 * HIDDEN / 128, M_ROWS / 128), 256, 0, stream>>>(h2, wgateT, gvb, nullptr, nullptr, M_ROWS, 2 * HIDDEN, DIM);
  // act = silu(g) * v
  k_silu<<<(M_ROWS * (HIDDEN / 8)) / 256, 256, 0, stream>>>(gvb, act);
  // out = x1 + act @ w_down
  k_gemm<1><<<dim3(DIM / 128, M_ROWS / 128), 256, 0, stream>>>(act, wdownT, nullptr, x1, outp, M_ROWS, DIM, HIDDEN);
}

// Round 3
// 975.556 us; speedup vs baseline: 1.0616x; 1.0616x over previous
//
#include <hip/hip_runtime.h>

#define DIM 2048
#define NH 16
#define HD 128
#define HIDDEN 5504
#define BB 2
#define TT 2048
#define M_ROWS (BB*TT)
#define QKV_N (3*DIM)
#define ATT_SCALE 0.08838834764831845f

typedef float f32x4 __attribute__((ext_vector_type(4)));
typedef __bf16 bf16x8 __attribute__((ext_vector_type(8)));

#define AS1 __attribute__((address_space(1)))
#define AS3 __attribute__((address_space(3)))

__device__ __forceinline__ float bf2f(unsigned short u){
  unsigned x = ((unsigned)u) << 16; float f; __builtin_memcpy(&f, &x, 4); return f;
}
__device__ __forceinline__ unsigned short f2bf(float f){
  unsigned x; __builtin_memcpy(&x, &f, 4);
  x = (x + 0x7fffu + ((x >> 16) & 1u)) >> 16;
  return (unsigned short)x;
}
__device__ __forceinline__ void gl_lds16(const unsigned short* g, unsigned short* l){
  __builtin_amdgcn_global_load_lds((AS1 const void*)(uintptr_t)g,
                                   (AS3 void*)(unsigned int)(uintptr_t)l, 16, 0, 0);
}

// ---------- transpose: src f32 (K x N) -> dst bf16 (N x K) ----------
__global__ __launch_bounds__(256) void k_transpose(const float* __restrict__ src,
                                                   unsigned short* __restrict__ dst,
                                                   int K, int N){
  __shared__ float tile[64][65];
  int nb = blockIdx.x * 64, kb = blockIdx.y * 64;
  int tid = threadIdx.x, c = tid & 63, r0 = tid >> 6;
  #pragma unroll
  for (int i = 0; i < 16; i++){
    int r = i * 4 + r0;
    tile[r][c] = src[(size_t)(kb + r) * N + nb + c];
  }
  __syncthreads();
  #pragma unroll
  for (int i = 0; i < 16; i++){
    int r = i * 4 + r0;
    dst[(size_t)(nb + r) * K + kb + c] = f2bf(tile[c][r]);
  }
}

// ---------- per-(b,h) V transpose ----------
__global__ __launch_bounds__(256) void k_vtrans(const unsigned short* __restrict__ qkv,
                                                unsigned short* __restrict__ Vt_g){
  int bh = blockIdx.z; int b = bh >> 4, h = bh & 15;
  int tb = blockIdx.x * 64, db = blockIdx.y * 64;
  const unsigned short* Vp = qkv + (size_t)b * TT * QKV_N + 2 * DIM + h * HD;
  __shared__ unsigned short tile[64][66];
  int tid = threadIdx.x, c = tid & 63, r0 = tid >> 6;
  #pragma unroll
  for (int i = 0; i < 16; i++){
    int r = i * 4 + r0;
    tile[r][c] = Vp[(size_t)(tb + r) * QKV_N + db + c];
  }
  __syncthreads();
  #pragma unroll
  for (int i = 0; i < 16; i++){
    int r = i * 4 + r0;
    Vt_g[((size_t)bh * HD + db + r) * TT + tb + c] = tile[c][r];
  }
}

// ---------- LayerNorm ----------
__global__ __launch_bounds__(256) void k_ln(const float* __restrict__ x,
                                            const float* __restrict__ g,
                                            const float* __restrict__ b,
                                            unsigned short* __restrict__ out){
  int row = blockIdx.x, tid = threadIdx.x;
  const float* xr = x + (size_t)row * DIM;
  int c0 = tid * 4, c1 = 1024 + tid * 4;
  float4 a = *(const float4*)(xr + c0);
  float4 c = *(const float4*)(xr + c1);
  float s  = a.x + a.y + a.z + a.w + c.x + c.y + c.z + c.w;
  float sq = a.x*a.x + a.y*a.y + a.z*a.z + a.w*a.w + c.x*c.x + c.y*c.y + c.z*c.z + c.w*c.w;
  #pragma unroll
  for (int off = 1; off < 64; off <<= 1){
    s  += __shfl_xor(s,  off);
    sq += __shfl_xor(sq, off);
  }
  __shared__ float red[8];
  int wave = tid >> 6;
  if ((tid & 63) == 0){ red[wave] = s; red[4 + wave] = sq; }
  __syncthreads();
  s  = red[0] + red[1] + red[2] + red[3];
  sq = red[4] + red[5] + red[6] + red[7];
  float mean = s * (1.f / DIM);
  float var  = sq * (1.f / DIM) - mean * mean;
  float rs   = rsqrtf(var + 1e-5f);
  float4 g0 = *(const float4*)(g + c0), g1 = *(const float4*)(g + c1);
  float4 b0 = *(const float4*)(b + c0), b1 = *(const float4*)(b + c1);
  ushort4 o0, o1;
  o0.x = f2bf((a.x - mean) * rs * g0.x + b0.x);
  o0.y = f2bf((a.y - mean) * rs * g0.y + b0.y);
  o0.z = f2bf((a.z - mean) * rs * g0.z + b0.z);
  o0.w = f2bf((a.w - mean) * rs * g0.w + b0.w);
  o1.x = f2bf((c.x - mean) * rs * g1.x + b1.x);
  o1.y = f2bf((c.y - mean) * rs * g1.y + b1.y);
  o1.z = f2bf((c.z - mean) * rs * g1.z + b1.z);
  o1.w = f2bf((c.w - mean) * rs * g1.w + b1.w);
  *(ushort4*)(out + (size_t)row * DIM + c0) = o0;
  *(ushort4*)(out + (size_t)row * DIM + c1) = o1;
}

// ---------- 256x256 8-phase GEMM: C[M,N] = A[M,K](bf16) * Bt[N,K]^T ----------
// EPI 0: bf16 store. EPI 1: Cf = res + acc (f32).
template<int EPI>
__global__ __launch_bounds__(512, 2) void k_gemm8(const unsigned short* __restrict__ A,
                                                  const unsigned short* __restrict__ Bt,
                                                  unsigned short* __restrict__ Cb,
                                                  const float* __restrict__ res,
                                                  float* __restrict__ Cf,
                                                  int M, int N, int K, int ntn){
  // [buf][A|B][256 rows x 64 cols] bf16, 128 KiB total
  __shared__ unsigned short lds[2][2][256 * 64];
  const int tid  = threadIdx.x;
  const int wave = tid >> 6, l = tid & 63;
  const int lg = l >> 4, lr = l & 15;
  const int wm = wave >> 2, wn = wave & 3;

  // bijective XCD swizzle (m204)
  const int nwg = gridDim.x;
  const int q8 = nwg >> 3, r8 = nwg & 7;
  const int xcd = blockIdx.x & 7, loc = blockIdx.x >> 3;
  const int wgid = (xcd < r8 ? xcd * (q8 + 1) : r8 * (q8 + 1) + (xcd - r8) * q8) + loc;
  const int tm = wgid / ntn, tn = wgid - tm * ntn;
  const int m0 = tm * 256, n0 = tn * 256;

  // staging: chunk = h*1024 + q*512 + wave*64 + l ; row=chunk>>3 ; phys slot = l&7
  // inverse-swizzled global slot = (l&7) ^ ((l>>3)&7)
  const int srow  = wave * 8 + (l >> 3);
  const int sslot = (l & 7) ^ ((l >> 3) & 7);
  const unsigned short* a_st = A  + (size_t)(m0 + srow) * K + sslot * 8;
  const unsigned short* b_st = Bt + (size_t)(n0 + srow) * K + sslot * 8;
  const int wch = wave * 64 * 8;  // wave chunk base in shorts

  f32x4 acc[8][4];
  #pragma unroll
  for (int i = 0; i < 8; i++)
    #pragma unroll
    for (int j = 0; j < 4; j++) acc[i][j] = (f32x4)0.f;

  const int ktiles = K >> 6;
  char* base = (char*)&lds[0][0][0];

  // prologue: stage tile 0 -> buf 0
  {
    unsigned short* A0 = (unsigned short*)(base);
    unsigned short* B0 = (unsigned short*)(base + 32768);
    #pragma unroll
    for (int h = 0; h < 2; h++)
      #pragma unroll
      for (int qq = 0; qq < 2; qq++){
        gl_lds16(a_st + (size_t)(h * 128 + qq * 64) * K, A0 + (h * 1024 + qq * 512) * 8 + wch);
        gl_lds16(b_st + (size_t)(h * 128 + qq * 64) * K, B0 + (h * 1024 + qq * 512) * 8 + wch);
      }
  }
  asm volatile("s_waitcnt vmcnt(0)" ::: "memory");
  __builtin_amdgcn_s_barrier();

  const unsigned swz = (unsigned)((lr & 7) << 4);
  const int arow = wm * 128 + lr;   // + mi*16
  const int brow = wn * 64 + lr;    // + nj*16

  for (int kt = 0; kt < ktiles; ++kt){
    const int cur = kt & 1;
    const char* Ab = base + cur * 65536;
    const char* Bb = Ab + 32768;
    unsigned short* Sa = (unsigned short*)(base + (cur ^ 1) * 65536);
    unsigned short* Sb = (unsigned short*)((char*)Sa + 32768);
    const size_t kpos = (size_t)((kt + 1 < ktiles) ? kt + 1 : kt) * 64;
    const unsigned short* ag = a_st + kpos;
    const unsigned short* bg = b_st + kpos;
    bf16x8 a[4], b[4];

    // ---- phase 1: A[0..3]k0 + B[0..3]k0 ; stage Ah0,Ah1,Bh0 ----
    #pragma unroll
    for (int mi = 0; mi < 4; mi++)
      a[mi] = *(const bf16x8*)(Ab + (arow + mi * 16) * 128 + ((lg * 16) ^ swz));
    #pragma unroll
    for (int nj = 0; nj < 4; nj++)
      b[nj] = *(const bf16x8*)(Bb + (brow + nj * 16) * 128 + ((lg * 16) ^ swz));
    gl_lds16(ag,                      Sa + wch);
    gl_lds16(ag + (size_t) 64 * K,    Sa + 512 * 8 + wch);
    gl_lds16(ag + (size_t)128 * K,    Sa + 1024 * 8 + wch);
    gl_lds16(ag + (size_t)192 * K,    Sa + 1536 * 8 + wch);
    gl_lds16(bg,                      Sb + wch);
    gl_lds16(bg + (size_t) 64 * K,    Sb + 512 * 8 + wch);
    __builtin_amdgcn_s_barrier();
    asm volatile("s_waitcnt lgkmcnt(0)" ::: "memory");
    __builtin_amdgcn_s_setprio(1);
    #pragma unroll
    for (int mi = 0; mi < 4; mi++)
      #pragma unroll
      for (int nj = 0; nj < 4; nj++)
        acc[mi][nj] = __builtin_amdgcn_mfma_f32_16x16x32_bf16(a[mi], b[nj], acc[mi][nj], 0, 0, 0);
    __builtin_amdgcn_s_setprio(0);
    __builtin_amdgcn_s_barrier();

    // ---- phase 2: A[4..7]k0 ; stage Bh1 ----
    #pragma unroll
    for (int mi = 0; mi < 4; mi++)
      a[mi] = *(const bf16x8*)(Ab + (arow + 64 + mi * 16) * 128 + ((lg * 16) ^ swz));
    gl_lds16(bg + (size_t)128 * K,    Sb + 1024 * 8 + wch);
    gl_lds16(bg + (size_t)192 * K,    Sb + 1536 * 8 + wch);
    __builtin_amdgcn_s_barrier();
    asm volatile("s_waitcnt lgkmcnt(0)" ::: "memory");
    __builtin_amdgcn_s_setprio(1);
    #pragma unroll
    for (int mi = 0; mi < 4; mi++)
      #pragma unroll
      for (int nj = 0; nj < 4; nj++)
        acc[4 + mi][nj] = __builtin_amdgcn_mfma_f32_16x16x32_bf16(a[mi], b[nj], acc[4 + mi][nj], 0, 0, 0);
    __builtin_amdgcn_s_setprio(0);
    __builtin_amdgcn_s_barrier();

    // ---- phase 3: A[0..3]k1 + B[0..3]k1 ----
    #pragma unroll
    for (int mi = 0; mi < 4; mi++)
      a[mi] = *(const bf16x8*)(Ab + (arow + mi * 16) * 128 + ((64 + lg * 16) ^ swz));
    #pragma unroll
    for (int nj = 0; nj < 4; nj++)
      b[nj] = *(const bf16x8*)(Bb + (brow + nj * 16) * 128 + ((64 + lg * 16) ^ swz));
    __builtin_amdgcn_s_barrier();
    asm volatile("s_waitcnt lgkmcnt(0)" ::: "memory");
    __builtin_amdgcn_s_setprio(1);
    #pragma unroll
    for (int mi = 0; mi < 4; mi++)
      #pragma unroll
      for (int nj = 0; nj < 4; nj++)
        acc[mi][nj] = __builtin_amdgcn_mfma_f32_16x16x32_bf16(a[mi], b[nj], acc[mi][nj], 0, 0, 0);
    __builtin_amdgcn_s_setprio(0);
    __builtin_amdgcn_s_barrier();

    // ---- phase 4: A[4..7]k1 ; drain stages ----
    #pragma unroll
    for (int mi = 0; mi < 4; mi++)
      a[mi] = *(const bf16x8*)(Ab + (arow + 64 + mi * 16) * 128 + ((64 + lg * 16) ^ swz));
    __builtin_amdgcn_s_barrier();
    asm volatile("s_waitcnt lgkmcnt(0)" ::: "memory");
    __builtin_amdgcn_s_setprio(1);
    #pragma unroll
    for (int mi = 0; mi < 4; mi++)
      #pragma unroll
      for (int nj = 0; nj < 4; nj++)
        acc[4 + mi][nj] = __builtin_amdgcn_mfma_f32_16x16x32_bf16(a[mi], b[nj], acc[4 + mi][nj], 0, 0, 0);
    __builtin_amdgcn_s_setprio(0);
    asm volatile("s_waitcnt vmcnt(0)" ::: "memory");
    __builtin_amdgcn_s_barrier();
  }

  #pragma unroll
  for (int mi = 0; mi < 8; mi++){
    const int mrow = m0 + wm * 128 + mi * 16 + lg * 4;
    #pragma unroll
    for (int r = 0; r < 4; r++){
      const int m = mrow + r;
      #pragma unroll
      for (int nj = 0; nj < 4; nj++){
        const int n = n0 + wn * 64 + nj * 16 + lr;
        if (EPI == 0)
          Cb[(size_t)m * N + n] = f2bf(acc[mi][nj][r]);
        else
          Cf[(size_t)m * N + n] = res[(size_t)m * N + n] + acc[mi][nj][r];
      }
    }
  }
}

// ---------- RoPE in-place ----------
__global__ __launch_bounds__(256) void k_rope(unsigned short* __restrict__ qkv,
                                              const float* __restrict__ cosp,
                                              const float* __restrict__ sinp){
  int gid = blockIdx.x * 256 + threadIdx.x;
  int m = gid >> 10;
  int rem = gid & 1023;
  int h = rem >> 6, d = rem & 63;
  int t = m & (TT - 1);
  size_t base = (size_t)m * QKV_N + h * HD;
  float c = cosp[t * 64 + d], s = sinp[t * 64 + d];
  float q1 = bf2f(qkv[base + d]), q2 = bf2f(qkv[base + 64 + d]);
  qkv[base + d]      = f2bf((q1 * c - q2 * s) * ATT_SCALE);
  qkv[base + 64 + d] = f2bf((q1 * s + q2 * c) * ATT_SCALE);
  size_t kb = base + DIM;
  float k1 = bf2f(qkv[kb + d]), k2 = bf2f(qkv[kb + 64 + d]);
  qkv[kb + d]      = f2bf(k1 * c - k2 * s);
  qkv[kb + 64 + d] = f2bf(k1 * s + k2 * c);
}

// ---------- flash attention ----------
__global__ __launch_bounds__(256) void k_attn(const unsigned short* __restrict__ qkv,
                                              const unsigned short* __restrict__ Vt_g,
                                              unsigned short* __restrict__ O){
  int qb = blockIdx.x;
  int bh = blockIdx.y;
  int b = bh >> 4, h = bh & 15;
  const unsigned short* Qp = qkv + (size_t)b * TT * QKV_N + h * HD;
  const unsigned short* Kp = Qp + DIM;
  __shared__ __align__(16) unsigned short Kt[64][136];
  __shared__ __align__(16) unsigned short Vt[128][72];
  __shared__ __align__(16) unsigned short Ps[4][32][72];
  int tid = threadIdx.x, wave = tid >> 6, lane = tid & 63, lg = lane >> 4, lr = lane & 15;
  int q0 = qb * 128 + wave * 32;
  bf16x8 qf[2][4];
  #pragma unroll
  for (int mi = 0; mi < 2; mi++)
    #pragma unroll
    for (int dc = 0; dc < 4; dc++)
      qf[mi][dc] = *(const bf16x8*)(Qp + (size_t)(q0 + mi * 16 + lr) * QKV_N + dc * 32 + lg * 8);
  f32x4 of[2][8];
  #pragma unroll
  for (int mi = 0; mi < 2; mi++)
    #pragma unroll
    for (int dj = 0; dj < 8; dj++)
      of[mi][dj] = (f32x4)0.f;
  float mrun[2] = {-1e30f, -1e30f}, lrun[2] = {0.f, 0.f};
  int ktmax = 2 * qb + 1;
  int sr = tid >> 4, sc8 = (tid & 15) * 8;
  int vr = tid >> 3, vc8 = (tid & 7) * 8;
  for (int kt = 0; kt <= ktmax; kt++){
    int kbase = kt * 64;
    __syncthreads();
    #pragma unroll
    for (int i = 0; i < 4; i++){
      int rr = sr + i * 16;
      *(int4*)(&Kt[rr][sc8]) = *(const int4*)(Kp + (size_t)(kbase + rr) * QKV_N + sc8);
      int dd = vr + i * 32;
      *(int4*)(&Vt[dd][vc8]) = *(const int4*)(Vt_g + ((size_t)bh * HD + dd) * TT + kbase + vc8);
    }
    __syncthreads();
    f32x4 st[4][2];
    #pragma unroll
    for (int kj = 0; kj < 4; kj++)
      #pragma unroll
      for (int mi = 0; mi < 2; mi++)
        st[kj][mi] = (f32x4)0.f;
    #pragma unroll
    for (int kj = 0; kj < 4; kj++){
      #pragma unroll
      for (int dc = 0; dc < 4; dc++){
        bf16x8 kf = *(const bf16x8*)(&Kt[kj * 16 + lr][dc * 32 + lg * 8]);
        st[kj][0] = __builtin_amdgcn_mfma_f32_16x16x32_bf16(kf, qf[0][dc], st[kj][0], 0, 0, 0);
        st[kj][1] = __builtin_amdgcn_mfma_f32_16x16x32_bf16(kf, qf[1][dc], st[kj][1], 0, 0, 0);
      }
    }
    #pragma unroll
    for (int kj = 0; kj < 4; kj++){
      int kg = kbase + kj * 16 + lg * 4;
      #pragma unroll
      for (int mi = 0; mi < 2; mi++){
        int qg = q0 + mi * 16 + lr;
        #pragma unroll
        for (int r = 0; r < 4; r++)
          if (kg + r > qg) st[kj][mi][r] = -1e30f;
      }
    }
    #pragma unroll
    for (int mi = 0; mi < 2; mi++){
      float mx = -1e30f;
      #pragma unroll
      for (int kj = 0; kj < 4; kj++)
        #pragma unroll
        for (int r = 0; r < 4; r++)
          mx = fmaxf(mx, st[kj][mi][r]);
      mx = fmaxf(mx, __shfl_xor(mx, 16));
      mx = fmaxf(mx, __shfl_xor(mx, 32));
      float mnew = fmaxf(mrun[mi], mx);
      float fsc = __expf(mrun[mi] - mnew);
      float rs = 0.f;
      #pragma unroll
      for (int kj = 0; kj < 4; kj++)
        #pragma unroll
        for (int r = 0; r < 4; r++){
          float p = __expf(st[kj][mi][r] - mnew);
          st[kj][mi][r] = p;
          rs += p;
        }
      rs += __shfl_xor(rs, 16);
      rs += __shfl_xor(rs, 32);
      lrun[mi] = lrun[mi] * fsc + rs;
      mrun[mi] = mnew;
      float fr[4];
      #pragma unroll
      for (int r = 0; r < 4; r++) fr[r] = __shfl(fsc, lg * 4 + r);
      #pragma unroll
      for (int dj = 0; dj < 8; dj++)
        #pragma unroll
        for (int r = 0; r < 4; r++)
          of[mi][dj][r] *= fr[r];
      #pragma unroll
      for (int kj = 0; kj < 4; kj++){
        ushort4 pk;
        pk.x = f2bf(st[kj][mi][0]);
        pk.y = f2bf(st[kj][mi][1]);
        pk.z = f2bf(st[kj][mi][2]);
        pk.w = f2bf(st[kj][mi][3]);
        *(ushort4*)(&Ps[wave][mi * 16 + lr][kj * 16 + lg * 4]) = pk;
      }
    }
    #pragma unroll
    for (int kc = 0; kc < 2; kc++){
      bf16x8 pf0 = *(const bf16x8*)(&Ps[wave][lr][kc * 32 + lg * 8]);
      bf16x8 pf1 = *(const bf16x8*)(&Ps[wave][16 + lr][kc * 32 + lg * 8]);
      #pragma unroll
      for (int dj = 0; dj < 8; dj++){
        bf16x8 vf = *(const bf16x8*)(&Vt[dj * 16 + lr][kc * 32 + lg * 8]);
        of[0][dj] = __builtin_amdgcn_mfma_f32_16x16x32_bf16(pf0, vf, of[0][dj], 0, 0, 0);
        of[1][dj] = __builtin_amdgcn_mfma_f32_16x16x32_bf16(pf1, vf, of[1][dj], 0, 0, 0);
      }
    }
  }
  #pragma unroll
  for (int mi = 0; mi < 2; mi++){
    float inv[4];
    #pragma unroll
    for (int r = 0; r < 4; r++) inv[r] = 1.f / __shfl(lrun[mi], lg * 4 + r);
    #pragma unroll
    for (int r = 0; r < 4; r++){
      int t = q0 + mi * 16 + lg * 4 + r;
      size_t rowb = ((size_t)b * TT + t) * DIM + h * HD;
      #pragma unroll
      for (int dj = 0; dj < 8; dj++)
        O[rowb + dj * 16 + lr] = f2bf(of[mi][dj][r] * inv[r]);
    }
  }
}

// ---------- SiLU(g)*v ----------
__global__ __launch_bounds__(256) void k_silu(const unsigned short* __restrict__ gv,
                                              unsigned short* __restrict__ act){
  int gid = blockIdx.x * 256 + threadIdx.x;
  unsigned m = (unsigned)gid / 688u;
  int j8 = (gid - (int)m * 688) * 8;
  const unsigned short* gp = gv + (size_t)m * (2 * HIDDEN) + j8;
  union { int4 v; unsigned short s[8]; } G, V, Ov;
  G.v = *(const int4*)(gp);
  V.v = *(const int4*)(gp + HIDDEN);
  #pragma unroll
  for (int j = 0; j < 8; j++){
    float g = bf2f(G.s[j]);
    float v = bf2f(V.s[j]);
    float sg = g / (1.f + __expf(-g));
    Ov.s[j] = f2bf(sg * v);
  }
  *(int4*)(act + (size_t)m * HIDDEN + j8) = Ov.v;
}

extern "C" void kernel_launch(void* const* d_in, const int* in_sizes, int n_in,
                              void* d_out, int out_size, void* d_ws, size_t ws_size,
                              hipStream_t stream){
  const float* x     = (const float*)d_in[0];
  const float* cosp  = (const float*)d_in[1];
  const float* sinp  = (const float*)d_in[2];
  const float* ln1g  = (const float*)d_in[4];
  const float* ln1b  = (const float*)d_in[5];
  const float* ln2g  = (const float*)d_in[6];
  const float* ln2b  = (const float*)d_in[7];
  const float* wqkv  = (const float*)d_in[8];
  const float* wout  = (const float*)d_in[9];
  const float* wgate = (const float*)d_in[10];
  const float* wdown = (const float*)d_in[11];
  float* outp = (float*)d_out;

  char* ws = (char*)d_ws;
  size_t off = 0;
  auto alloc = [&](size_t bytes) -> void* {
    void* p = ws + off;
    off += (bytes + 255) & ~(size_t)255;
    return p;
  };
  unsigned short* wqkvT  = (unsigned short*)alloc((size_t)QKV_N * DIM * 2);
  unsigned short* woutT  = (unsigned short*)alloc((size_t)DIM * DIM * 2);
  unsigned short* wgateT = (unsigned short*)alloc((size_t)2 * HIDDEN * DIM * 2);
  unsigned short* wdownT = (unsigned short*)alloc((size_t)DIM * HIDDEN * 2);
  float*          x1     = (float*)alloc((size_t)M_ROWS * DIM * 4);
  unsigned short* h1     = (unsigned short*)alloc((size_t)M_ROWS * DIM * 2);
  unsigned short* h2     = (unsigned short*)alloc((size_t)M_ROWS * DIM * 2);
  unsigned short* act    = (unsigned short*)alloc((size_t)M_ROWS * HIDDEN * 2);
  unsigned short* Vt_g   = (unsigned short*)alloc((size_t)BB * NH * HD * TT * 2);
  unsigned short* big    = (unsigned short*)alloc((size_t)M_ROWS * 2 * HIDDEN * 2);
  unsigned short* qkvb = big;
  unsigned short* gvb  = big;
  unsigned short* Obuf = h1;
  (void)ws_size; (void)in_sizes; (void)n_in; (void)out_size;

  k_transpose<<<dim3(QKV_N / 64, DIM / 64), 256, 0, stream>>>(wqkv, wqkvT, DIM, QKV_N);
  k_transpose<<<dim3(DIM / 64, DIM / 64), 256, 0, stream>>>(wout, woutT, DIM, DIM);
  k_transpose<<<dim3(2 * HIDDEN / 64, DIM / 64), 256, 0, stream>>>(wgate, wgateT, DIM, 2 * HIDDEN);
  k_transpose<<<dim3(DIM / 64, HIDDEN / 64), 256, 0, stream>>>(wdown, wdownT, HIDDEN, DIM);
  k_ln<<<M_ROWS, 256, 0, stream>>>(x, ln1g, ln1b, h1);
  // qkv = h1 @ w_qkv   (M=4096, N=6144, K=2048)
  k_gemm8<0><<<(M_ROWS / 256) * (QKV_N / 256), 512, 0, stream>>>(h1, wqkvT, qkvb, nullptr, nullptr, M_ROWS, QKV_N, DIM, QKV_N / 256);
  k_rope<<<(M_ROWS * NH * 64) / 256, 256, 0, stream>>>(qkvb, cosp, sinp);
  k_vtrans<<<dim3(TT / 64, HD / 64, BB * NH), 256, 0, stream>>>(qkvb, Vt_g);
  k_attn<<<dim3(TT / 128, BB * NH), 256, 0, stream>>>(qkvb, Vt_g, Obuf);
  // x1 = x + O @ w_out  (N=2048)
  k_gemm8<1><<<(M_ROWS / 256) * (DIM / 256), 512, 0, stream>>>(Obuf, woutT, nullptr, x, x1, M_ROWS, DIM, DIM, DIM / 256);
  k_ln<<<M_ROWS, 256, 0, stream>>>(x1, ln2g, ln2b, h2);
  // gv = h2 @ w_gate   (N=11008)
  k_gemm8<0><<<(M_ROWS / 256) * (2 * HIDDEN / 256), 512, 0, stream>>>(h2, wgateT, gvb, nullptr, nullptr, M_ROWS, 2 * HIDDEN, DIM, 2 * HIDDEN / 256);
  k_silu<<<(M_ROWS * (HIDDEN / 8)) / 256, 256, 0, stream>>>(gvb, act);
  // out = x1 + act @ w_down  (N=2048, K=5504)
  k_gemm8<1><<<(M_ROWS / 256) * (DIM / 256), 512, 0, stream>>>(act, wdownT, nullptr, x1, outp, M_ROWS, DIM, HIDDEN, DIM / 256);
}